// Round 2
// 956.235 us; speedup vs baseline: 3.0740x; 3.0740x over previous
//
#include <hip/hip_runtime.h>
#include <hip/hip_bf16.h>

// Problem constants: B=256, F=64, H=W=64, D=256, HC=32
// d_in: 0:x(256,256) 1:state(256,64,64,64) 2:index(256,2) 3:c1w 4:c1b 5:c2w 6:c2b
//       7:c3w 8:c3b 9:lin_w(131072,64) 10:lin_b 11:write_w(384,64) 12:write_b
// d_out: out(256,128) fp32 ++ new_state(256,64,64,64) fp32
// Scratch: repacked weights live in the out region (overwritten by lin_reduce/write_k);
// h1/h2/h3/partial live inside new_state until copy_state_k runs.

typedef __attribute__((ext_vector_type(8))) short bf16x8;
typedef __attribute__((ext_vector_type(4))) float f32x4;

__device__ inline unsigned short f2bfu(float f) {
    __hip_bfloat16 h = __float2bfloat16(f);
    return *reinterpret_cast<unsigned short*>(&h);
}

// ---------------------------------------------------------------------------
// Weight repack: (32, CIN, 3, 3) fp32 -> [ch][ks][co][ci_l] bf16, MFMA A-frag
// order: lane (co = l&15 (+16*cg), ci slice = (l>>4)*8) reads 16B contiguous.
// rw layout: conv1 = 18432 elems (2 chunks), conv2 = 9216, conv3 = 9216.
// ---------------------------------------------------------------------------
__global__ __launch_bounds__(256)
void repack_w_k(const float* __restrict__ w1, const float* __restrict__ w2,
                const float* __restrict__ w3, __hip_bfloat16* __restrict__ rw)
{
    int idx = blockIdx.x * 256 + threadIdx.x;          // 36864 total
    const float* src; int CIN, li;
    if (idx < 18432)      { src = w1; CIN = 64; li = idx; }
    else if (idx < 27648) { src = w2; CIN = 32; li = idx - 18432; }
    else                  { src = w3; CIN = 32; li = idx - 27648; }
    int ci = li & 31;
    int co = (li >> 5) & 31;
    int t2 = li >> 10;            // = ch*9 + ks
    int ks = t2 % 9;
    int ch = t2 / 9;
    rw[idx] = __float2bfloat16(src[((size_t)(co * CIN + ch * 32 + ci)) * 9 + ks]);
}

// ---------------------------------------------------------------------------
// Implicit-GEMM 3x3 SAME conv + bias + relu via MFMA 16x16x32 bf16.
// Block: 256 thr (4 waves), one image, 16(y)x32(x) output tile, all 32 co.
// Wave: 8 pixel-groups of 16 px, 2 co-groups -> 16 fragments (64 acc VGPR).
// Weights (A-frags) in registers; input tile in LDS [18][34][40] bf16.
// TIN=float  -> NCHW fp32 input (conv1, CIN=64, 2 ci-chunks, transpose staging)
// TIN=bf16   -> NHWC bf16 input (conv2/3, CIN=32, 16B vector staging)
// Output NHWC bf16 (256, 64, 64, 32).
// ---------------------------------------------------------------------------
template<int CIN, typename TIN>
__global__ __launch_bounds__(256, 2)
void conv_mfma_k(const TIN* __restrict__ in,
                 const __hip_bfloat16* __restrict__ rw,   // [CIN/32][9][32][32]
                 const float* __restrict__ bias,          // (32)
                 __hip_bfloat16* __restrict__ out)        // (256, 64, 64, 32)
{
    constexpr int NCH = CIN / 32;
    __shared__ __hip_bfloat16 s_in[18 * 34 * 40];   // 48,960 B; px stride 80 B

    const int b    = blockIdx.x;
    const int ty0  = (blockIdx.y >> 1) * 16;
    const int tx0  = (blockIdx.y & 1) * 32;
    const int t    = threadIdx.x;
    const int lane = t & 63;
    const int wv   = t >> 6;          // wave 0..3
    const int ln   = lane & 15;       // A: co row / B: pixel col
    const int lg   = lane >> 4;       // k-slice group (8 elems each)

    const f32x4 zero4 = {0.f, 0.f, 0.f, 0.f};
    f32x4 acc[8][2];
    #pragma unroll
    for (int p = 0; p < 8; ++p) { acc[p][0] = zero4; acc[p][1] = zero4; }

    // per-pixel-group LDS byte base: pixel (y = gg>>1, x = (gg&1)*16 + ln)
    int bbase[8];
    #pragma unroll
    for (int p = 0; p < 8; ++p) {
        int gg = wv * 8 + p;
        bbase[p] = (((gg >> 1) * 34) + (gg & 1) * 16 + ln) * 80 + lg * 16;
    }

    for (int ch = 0; ch < NCH; ++ch) {
        // ---- A fragments (weights) -> registers, 16B/lane, L2-hot
        bf16x8 wf[9][2];
        #pragma unroll
        for (int ks = 0; ks < 9; ++ks)
            #pragma unroll
            for (int cg = 0; cg < 2; ++cg)
                wf[ks][cg] = *(const bf16x8*)(rw + ((size_t)((ch * 9 + ks) * 32 + cg * 16 + ln)) * 32 + lg * 8);

        // ---- stage input halo tile for this ci-chunk
        if constexpr (sizeof(TIN) == 4) {
            // NCHW fp32: scalar transpose + convert (HBM-bound anyway)
            for (int idx = t; idx < 32 * 18 * 34; idx += 256) {
                int lx = idx % 34;
                int r  = idx / 34;
                int ly = r % 18;
                int ci = r / 18;
                int gy = ty0 - 1 + ly, gx = tx0 - 1 + lx;
                float v = 0.f;
                if ((unsigned)gy < 64u && (unsigned)gx < 64u)
                    v = in[(((size_t)b * CIN + ch * 32 + ci) * 64 + gy) * 64 + gx];
                s_in[(ly * 34 + lx) * 40 + ci] = __float2bfloat16(v);
            }
        } else {
            // NHWC bf16: TRUE 16B vector copy per (pixel, ci-octet)
            for (int idx = t; idx < 18 * 34 * 4; idx += 256) {
                int c8 = idx & 3, px = idx >> 2;
                int ly = px / 34, lx = px - ly * 34;
                int gy = ty0 - 1 + ly, gx = tx0 - 1 + lx;
                uint4 v = make_uint4(0u, 0u, 0u, 0u);   // 16 bytes = 8 bf16
                if ((unsigned)gy < 64u && (unsigned)gx < 64u)
                    v = *(const uint4*)(in + ((size_t)b * 4096 + gy * 64 + gx) * 32 + c8 * 8);
                *(uint4*)(reinterpret_cast<char*>(s_in) + px * 80 + c8 * 16) = v;
            }
        }
        __syncthreads();

        // ---- 9 shifted K=32 GEMM steps
        #pragma unroll
        for (int ky = 0; ky < 3; ++ky)
        #pragma unroll
        for (int kx = 0; kx < 3; ++kx) {
            const int ks   = ky * 3 + kx;
            const int koff = (ky * 34 + kx) * 80;
            #pragma unroll
            for (int p = 0; p < 8; ++p) {
                bf16x8 bfr = *(const bf16x8*)(reinterpret_cast<const char*>(s_in) + bbase[p] + koff);
                acc[p][0] = __builtin_amdgcn_mfma_f32_16x16x32_bf16(wf[ks][0], bfr, acc[p][0], 0, 0, 0);
                acc[p][1] = __builtin_amdgcn_mfma_f32_16x16x32_bf16(wf[ks][1], bfr, acc[p][1], 0, 0, 0);
            }
        }
        __syncthreads();
    }

    // ---- epilogue: bias + relu, packed NHWC store (4 consecutive co = 8B)
    #pragma unroll
    for (int p = 0; p < 8; ++p) {
        int gg = wv * 8 + p;
        int y  = ty0 + (gg >> 1);
        int x  = tx0 + (gg & 1) * 16 + ln;
        size_t pxb = ((size_t)b * 4096 + y * 64 + x) * 32;
        #pragma unroll
        for (int cg = 0; cg < 2; ++cg) {
            int co0 = cg * 16 + lg * 4;   // D row = (lane>>4)*4 + reg
            float4 bv = *(const float4*)(bias + co0);
            ushort4 o;                    // 8 B = 4 bf16 (intended here)
            o.x = f2bfu(fmaxf(acc[p][cg][0] + bv.x, 0.f));
            o.y = f2bfu(fmaxf(acc[p][cg][1] + bv.y, 0.f));
            o.z = f2bfu(fmaxf(acc[p][cg][2] + bv.z, 0.f));
            o.w = f2bfu(fmaxf(acc[p][cg][3] + bv.w, 0.f));
            *(ushort4*)(out + pxb + co0) = o;
        }
    }
}

// ---------------------------------------------------------------------------
// Linear stage 1: split-K GEMM. M=256(b) N=64(f) K=131072. h3 is NHWC bf16,
// so k enumerates (yx, co); lin_w row = co*4096 + yx (NCHW flattening).
// ---------------------------------------------------------------------------
__global__ __launch_bounds__(256)
void lin_partial_k(const __hip_bfloat16* __restrict__ h3,  // (256, 131072) NHWC order
                   const float* __restrict__ lw,           // (131072, 64) NCHW order
                   float* __restrict__ partial)            // (256, 256*64)
{
    __shared__ float s_h[32][260];
    __shared__ float s_w[32][64];
    const int t  = threadIdx.x;
    const int k0 = blockIdx.x * 512;
    const int f0 = (t & 15) * 4;
    const int b0 = (t >> 4) * 16;

    float acc[16][4];
    #pragma unroll
    for (int i = 0; i < 16; ++i)
        #pragma unroll
        for (int j = 0; j < 4; ++j) acc[i][j] = 0.f;

    for (int kk = 0; kk < 512; kk += 32) {
        #pragma unroll
        for (int i = 0; i < 8; ++i) {
            int id = i * 256 + t;
            int bb = id >> 3;
            int pc = id & 7;
            ushort4 hv = *(const ushort4*)(h3 + (size_t)bb * 131072 + k0 + kk + pc * 4);  // 4 bf16 = 8 B
            s_h[pc * 4 + 0][bb] = __uint_as_float((unsigned)hv.x << 16);
            s_h[pc * 4 + 1][bb] = __uint_as_float((unsigned)hv.y << 16);
            s_h[pc * 4 + 2][bb] = __uint_as_float((unsigned)hv.z << 16);
            s_h[pc * 4 + 3][bb] = __uint_as_float((unsigned)hv.w << 16);
        }
        #pragma unroll
        for (int i = 0; i < 2; ++i) {
            int id = i * 256 + t;
            int kr = id >> 4;
            int c4 = (id & 15) * 4;
            int k  = k0 + kk + kr;
            size_t ref = (size_t)(k & 31) * 4096 + (size_t)(k >> 5);   // co*4096 + yx
            float4 wv = *(const float4*)&lw[ref * 64 + c4];
            *(float4*)&s_w[kr][c4] = wv;
        }
        __syncthreads();
        for (int k = 0; k < 32; ++k) {
            float4 wv = *(const float4*)&s_w[k][f0];
            #pragma unroll
            for (int ii = 0; ii < 4; ++ii) {
                float4 hv = *(const float4*)&s_h[k][b0 + ii * 4];
                float hvv[4] = {hv.x, hv.y, hv.z, hv.w};
                #pragma unroll
                for (int l = 0; l < 4; ++l) {
                    acc[ii * 4 + l][0] += hvv[l] * wv.x;
                    acc[ii * 4 + l][1] += hvv[l] * wv.y;
                    acc[ii * 4 + l][2] += hvv[l] * wv.z;
                    acc[ii * 4 + l][3] += hvv[l] * wv.w;
                }
            }
        }
        __syncthreads();
    }

    float* pp = partial + (size_t)blockIdx.x * 16384;
    #pragma unroll
    for (int i = 0; i < 16; ++i) {
        float4 v = make_float4(acc[i][0], acc[i][1], acc[i][2], acc[i][3]);
        *(float4*)&pp[(b0 + i) * 64 + f0] = v;
    }
}

// Stage 2: reduce 256 partials, + bias, relu, write r into out[b*128 + f].
__global__ __launch_bounds__(256)
void lin_reduce_k(const float* __restrict__ partial,
                  const float* __restrict__ lb,
                  float* __restrict__ out)
{
    int idx = blockIdx.x * 256 + threadIdx.x;   // 16384
    int b = idx >> 6, f = idx & 63;
    float s = lb[f];
    for (int c = 0; c < 256; ++c) s += partial[(size_t)c * 16384 + idx];
    out[(size_t)b * 128 + f] = fmaxf(s, 0.f);
}

// w = [x | r | m] @ write_w + write_b  -> out[b*128 + 64 + f]
__global__ __launch_bounds__(256)
void write_k(const float* __restrict__ x,
             const float* __restrict__ state,
             const int* __restrict__ index,
             const float* __restrict__ ww,
             const float* __restrict__ wb,
             float* __restrict__ out)
{
    int idx = blockIdx.x * 256 + threadIdx.x;   // 16384
    int b = idx >> 6, f = idx & 63;
    int i0 = index[b * 2 + 0];
    int i1 = index[b * 2 + 1];
    float s = wb[f];
    for (int k = 0; k < 256; ++k) s += x[(size_t)b * 256 + k] * ww[k * 64 + f];
    for (int k = 0; k < 64; ++k)  s += out[(size_t)b * 128 + k] * ww[(256 + k) * 64 + f];
    const float* mp = state + (size_t)b * 262144 + (size_t)i0 * 64 + i1;
    for (int k = 0; k < 64; ++k)  s += mp[(size_t)k * 4096] * ww[(320 + k) * 64 + f];
    out[(size_t)b * 128 + 64 + f] = s;
}

__global__ __launch_bounds__(256)
void copy_state_k(const float4* __restrict__ src, float4* __restrict__ dst, int n4)
{
    int stride = gridDim.x * blockDim.x;
    for (int i = blockIdx.x * blockDim.x + threadIdx.x; i < n4; i += stride)
        dst[i] = src[i];
}

__global__ __launch_bounds__(256)
void scatter_k(const int* __restrict__ index,
               const float* __restrict__ out_ro,
               float* __restrict__ ns)
{
    int idx = blockIdx.x * 256 + threadIdx.x;   // 16384
    int b = idx >> 6, f = idx & 63;
    int i0 = index[b * 2 + 0];
    int i1 = index[b * 2 + 1];
    ns[(((size_t)b * 64 + f) * 64 + i0) * 64 + i1] = out_ro[(size_t)b * 128 + 64 + f];
}

extern "C" void kernel_launch(void* const* d_in, const int* in_sizes, int n_in,
                              void* d_out, int out_size, void* d_ws, size_t ws_size,
                              hipStream_t stream)
{
    (void)in_sizes; (void)n_in; (void)out_size; (void)d_ws; (void)ws_size;
    const float* x     = (const float*)d_in[0];
    const float* state = (const float*)d_in[1];
    const int*   idx   = (const int*)d_in[2];
    const float* c1w   = (const float*)d_in[3];
    const float* c1b   = (const float*)d_in[4];
    const float* c2w   = (const float*)d_in[5];
    const float* c2b   = (const float*)d_in[6];
    const float* c3w   = (const float*)d_in[7];
    const float* c3b   = (const float*)d_in[8];
    const float* lw    = (const float*)d_in[9];
    const float* lb    = (const float*)d_in[10];
    const float* ww    = (const float*)d_in[11];
    const float* wb    = (const float*)d_in[12];

    float* out = (float*)d_out;
    float* ns  = out + 32768;                       // new_state region = scratch until copy

    // Repacked weights: 36,864 bf16 = 72 KB in the out region (out is 128 KB,
    // fully rewritten later by lin_reduce_k + write_k).
    __hip_bfloat16* rw  = (__hip_bfloat16*)out;
    __hip_bfloat16* rw1 = rw;                       // 18432 elems (CIN=64, 2 chunks)
    __hip_bfloat16* rw2 = rw + 18432;               // 9216
    __hip_bfloat16* rw3 = rw + 27648;               // 9216

    // NHWC bf16 intermediates inside new_state region (256 MB):
    __hip_bfloat16* h1 = (__hip_bfloat16*)ns;       // [0, 64 MB)
    __hip_bfloat16* h2 = h1 + 33554432;             // [64 MB, 128 MB)
    __hip_bfloat16* h3 = h1;                        // conv3 reads h2, reuses h1 space
    float* partial     = (float*)h2;                // 16 MB, reuses h2 space after conv3

    repack_w_k<<<144, 256, 0, stream>>>(c1w, c2w, c3w, rw);
    conv_mfma_k<64, float>         <<<dim3(256, 8), 256, 0, stream>>>(state, rw1, c1b, h1);
    conv_mfma_k<32, __hip_bfloat16><<<dim3(256, 8), 256, 0, stream>>>(h1, rw2, c2b, h2);
    conv_mfma_k<32, __hip_bfloat16><<<dim3(256, 8), 256, 0, stream>>>(h2, rw3, c3b, h3);
    lin_partial_k<<<256, 256, 0, stream>>>(h3, lw, partial);
    lin_reduce_k <<<64, 256, 0, stream>>>(partial, lb, out);
    write_k      <<<64, 256, 0, stream>>>(x, state, idx, ww, wb, out);
    copy_state_k <<<8192, 256, 0, stream>>>((const float4*)state, (float4*)ns, 16777216);
    scatter_k    <<<64, 256, 0, stream>>>(idx, out, ns);
}

// Round 3
// 846.204 us; speedup vs baseline: 3.4737x; 1.1300x over previous
//
#include <hip/hip_runtime.h>
#include <hip/hip_bf16.h>

// Problem constants: B=256, F=64, H=W=64, D=256, HC=32
// d_in: 0:x(256,256) 1:state(256,64,64,64) 2:index(256,2) 3:c1w 4:c1b 5:c2w 6:c2b
//       7:c3w 8:c3b 9:lin_w(131072,64) 10:lin_b 11:write_w(384,64) 12:write_b
// d_out: out(256,128) fp32 ++ new_state(256,64,64,64) fp32
// Scratch map (inside new_state region, 256 MB, dead until copy_state_k):
//   [  0, 64MB)  h1 (NHWC bf16)      [ 64,128MB)  h2 / partial
//   [128,256MB)  state in NHWC bf16 (prepass output)
// Repacked conv weights (72 KB) live in the out region (rewritten later).

typedef __attribute__((ext_vector_type(8))) short bf16x8;
typedef __attribute__((ext_vector_type(4))) float f32x4;

__device__ inline unsigned short f2bfu(float f) {
    __hip_bfloat16 h = __float2bfloat16(f);
    return *reinterpret_cast<unsigned short*>(&h);
}

// ---------------------------------------------------------------------------
// Weight repack: (32, CIN, 3, 3) fp32 -> [ch][ks][co][ci_l] bf16, MFMA A-frag
// order: lane (co = l&15 (+16*cg), ci slice = (l>>4)*8) reads 16B contiguous.
// ---------------------------------------------------------------------------
__global__ __launch_bounds__(256)
void repack_w_k(const float* __restrict__ w1, const float* __restrict__ w2,
                const float* __restrict__ w3, __hip_bfloat16* __restrict__ rw)
{
    int idx = blockIdx.x * 256 + threadIdx.x;          // 36864 total
    const float* src; int CIN, li;
    if (idx < 18432)      { src = w1; CIN = 64; li = idx; }
    else if (idx < 27648) { src = w2; CIN = 32; li = idx - 18432; }
    else                  { src = w3; CIN = 32; li = idx - 27648; }
    int ci = li & 31;
    int co = (li >> 5) & 31;
    int t2 = li >> 10;            // = ch*9 + ks
    int ks = t2 % 9;
    int ch = t2 / 9;
    rw[idx] = __float2bfloat16(src[((size_t)(co * CIN + ch * 32 + ci)) * 9 + ks]);
}

// ---------------------------------------------------------------------------
// NCHW fp32 -> NHWC bf16 transpose prepass. One block per (b, y): read
// [64c][64x] coalesced (256B rows), LDS transpose, write [64x][64c] contiguous.
// ---------------------------------------------------------------------------
__global__ __launch_bounds__(256)
void nchw_to_nhwc_k(const float* __restrict__ in,          // (256,64,64,64) NCHW
                    __hip_bfloat16* __restrict__ outp)     // (256,64,64,64) b,y,x,c
{
    __shared__ unsigned short s[64][72];   // bf16 [c][x]; stride 144B: 8B-aligned, ~2-way banks
    const int blk = blockIdx.x;            // 16384 = 256 b * 64 y
    const int b = blk >> 6, y = blk & 63;
    const int t = threadIdx.x;

    const float* src = in + (size_t)b * 262144 + (size_t)y * 64;    // + c*4096 + x
    #pragma unroll
    for (int q = 0; q < 4; ++q) {
        int c = q * 16 + (t >> 4);
        int x = (t & 15) * 4;
        float4 v = *(const float4*)(src + (size_t)c * 4096 + x);
        *(ushort4*)&s[c][x] = make_ushort4(f2bfu(v.x), f2bfu(v.y), f2bfu(v.z), f2bfu(v.w));
    }
    __syncthreads();

    __hip_bfloat16* dst = outp + ((size_t)b * 4096 + y * 64) * 64;  // + x*64 + c
    #pragma unroll
    for (int q = 0; q < 4; ++q) {
        int x = q * 16 + (t >> 4);
        int c = (t & 15) * 4;
        ushort4 o = make_ushort4(s[c + 0][x], s[c + 1][x], s[c + 2][x], s[c + 3][x]);
        *(ushort4*)(dst + (size_t)x * 64 + c) = o;
    }
}

// ---------------------------------------------------------------------------
// Implicit-GEMM 3x3 SAME conv + bias + relu via MFMA 16x16x32 bf16.
// Block: 256 thr (4 waves), one image, 16(y)x32(x) output tile, all 32 co.
// Wave: 8 pixel-groups of 16 px, 2 co-groups -> 16 fragments (64 acc VGPR).
// Input NHWC bf16; staging = batched 16B loads -> regs -> LDS [px*80B + c8*16B].
// Output NHWC bf16 (256, 64, 64, 32). 3 blocks/CU (LDS 49KB*3 = 147KB).
// ---------------------------------------------------------------------------
template<int CIN>
__global__ __launch_bounds__(256, 3)
void conv_mfma_k(const __hip_bfloat16* __restrict__ in,   // (256,64,64,CIN) NHWC
                 const __hip_bfloat16* __restrict__ rw,   // [CIN/32][9][32][32]
                 const float* __restrict__ bias,          // (32)
                 __hip_bfloat16* __restrict__ out)        // (256,64,64,32) NHWC
{
    constexpr int NCH = CIN / 32;
    __shared__ __hip_bfloat16 s_in[18 * 34 * 40];   // 48,960 B; px stride 80 B

    const int b    = blockIdx.x;
    const int ty0  = (blockIdx.y >> 1) * 16;
    const int tx0  = (blockIdx.y & 1) * 32;
    const int t    = threadIdx.x;
    const int lane = t & 63;
    const int wv   = t >> 6;          // wave 0..3
    const int ln   = lane & 15;       // A: co row / B: pixel col
    const int lg   = lane >> 4;       // k-slice group (8 elems each)

    const f32x4 zero4 = {0.f, 0.f, 0.f, 0.f};
    f32x4 acc[8][2];
    #pragma unroll
    for (int p = 0; p < 8; ++p) { acc[p][0] = zero4; acc[p][1] = zero4; }

    // per-pixel-group LDS byte base: pixel (y = gg>>1, x = (gg&1)*16 + ln)
    int bbase[8];
    #pragma unroll
    for (int p = 0; p < 8; ++p) {
        int gg = wv * 8 + p;
        bbase[p] = (((gg >> 1) * 34) + (gg & 1) * 16 + ln) * 80 + lg * 16;
    }

    for (int ch = 0; ch < NCH; ++ch) {
        // ---- A fragments (weights) -> registers, 16B/lane, L2-hot
        bf16x8 wf[9][2];
        #pragma unroll
        for (int ks = 0; ks < 9; ++ks)
            #pragma unroll
            for (int cg = 0; cg < 2; ++cg)
                wf[ks][cg] = *(const bf16x8*)(rw + ((size_t)((ch * 9 + ks) * 32 + cg * 16 + ln)) * 32 + lg * 8);

        // ---- stage halo tile: 612 px x 4 chunks of 16B = 2448 ids, 10 passes.
        // Batch all loads into regs first (MLP), then LDS writes.
        uint4 vreg[10];
        #pragma unroll
        for (int q = 0; q < 10; ++q) {
            int id = q * 256 + t;
            uint4 v = make_uint4(0u, 0u, 0u, 0u);
            if (id < 2448) {
                int c8 = id & 3, px = id >> 2;
                int ly = px / 34, lx = px - ly * 34;
                int gy = ty0 - 1 + ly, gx = tx0 - 1 + lx;
                if ((unsigned)gy < 64u && (unsigned)gx < 64u)
                    v = *(const uint4*)(in + ((size_t)b * 4096 + gy * 64 + gx) * CIN + ch * 32 + c8 * 8);
            }
            vreg[q] = v;
        }
        #pragma unroll
        for (int q = 0; q < 10; ++q) {
            int id = q * 256 + t;
            if (id < 2448) {
                int c8 = id & 3, px = id >> 2;
                *(uint4*)(reinterpret_cast<char*>(s_in) + px * 80 + c8 * 16) = vreg[q];
            }
        }
        __syncthreads();

        // ---- 9 shifted K=32 GEMM steps
        #pragma unroll
        for (int ky = 0; ky < 3; ++ky)
        #pragma unroll
        for (int kx = 0; kx < 3; ++kx) {
            const int ks   = ky * 3 + kx;
            const int koff = (ky * 34 + kx) * 80;
            #pragma unroll
            for (int p = 0; p < 8; ++p) {
                bf16x8 bfr = *(const bf16x8*)(reinterpret_cast<const char*>(s_in) + bbase[p] + koff);
                acc[p][0] = __builtin_amdgcn_mfma_f32_16x16x32_bf16(wf[ks][0], bfr, acc[p][0], 0, 0, 0);
                acc[p][1] = __builtin_amdgcn_mfma_f32_16x16x32_bf16(wf[ks][1], bfr, acc[p][1], 0, 0, 0);
            }
        }
        __syncthreads();
    }

    // ---- epilogue: bias + relu, packed NHWC store (4 consecutive co = 8B)
    #pragma unroll
    for (int p = 0; p < 8; ++p) {
        int gg = wv * 8 + p;
        int y  = ty0 + (gg >> 1);
        int x  = tx0 + (gg & 1) * 16 + ln;
        size_t pxb = ((size_t)b * 4096 + y * 64 + x) * 32;
        #pragma unroll
        for (int cg = 0; cg < 2; ++cg) {
            int co0 = cg * 16 + lg * 4;   // D row = (lane>>4)*4 + reg
            float4 bv = *(const float4*)(bias + co0);
            ushort4 o;
            o.x = f2bfu(fmaxf(acc[p][cg][0] + bv.x, 0.f));
            o.y = f2bfu(fmaxf(acc[p][cg][1] + bv.y, 0.f));
            o.z = f2bfu(fmaxf(acc[p][cg][2] + bv.z, 0.f));
            o.w = f2bfu(fmaxf(acc[p][cg][3] + bv.w, 0.f));
            *(ushort4*)(out + pxb + co0) = o;
        }
    }
}

// ---------------------------------------------------------------------------
// Linear stage 1: split-K GEMM. M=256(b) N=64(f) K=131072. h3 is NHWC bf16,
// so k enumerates (yx, co); lin_w row = co*4096 + yx (NCHW flattening).
// ---------------------------------------------------------------------------
__global__ __launch_bounds__(256)
void lin_partial_k(const __hip_bfloat16* __restrict__ h3,  // (256, 131072) NHWC order
                   const float* __restrict__ lw,           // (131072, 64) NCHW order
                   float* __restrict__ partial)            // (256, 256*64)
{
    __shared__ float s_h[32][260];
    __shared__ float s_w[32][64];
    const int t  = threadIdx.x;
    const int k0 = blockIdx.x * 512;
    const int f0 = (t & 15) * 4;
    const int b0 = (t >> 4) * 16;

    float acc[16][4];
    #pragma unroll
    for (int i = 0; i < 16; ++i)
        #pragma unroll
        for (int j = 0; j < 4; ++j) acc[i][j] = 0.f;

    for (int kk = 0; kk < 512; kk += 32) {
        #pragma unroll
        for (int i = 0; i < 8; ++i) {
            int id = i * 256 + t;
            int bb = id >> 3;
            int pc = id & 7;
            ushort4 hv = *(const ushort4*)(h3 + (size_t)bb * 131072 + k0 + kk + pc * 4);  // 4 bf16 = 8 B
            s_h[pc * 4 + 0][bb] = __uint_as_float((unsigned)hv.x << 16);
            s_h[pc * 4 + 1][bb] = __uint_as_float((unsigned)hv.y << 16);
            s_h[pc * 4 + 2][bb] = __uint_as_float((unsigned)hv.z << 16);
            s_h[pc * 4 + 3][bb] = __uint_as_float((unsigned)hv.w << 16);
        }
        #pragma unroll
        for (int i = 0; i < 2; ++i) {
            int id = i * 256 + t;
            int kr = id >> 4;
            int c4 = (id & 15) * 4;
            int k  = k0 + kk + kr;
            size_t ref = (size_t)(k & 31) * 4096 + (size_t)(k >> 5);   // co*4096 + yx
            float4 wv = *(const float4*)&lw[ref * 64 + c4];
            *(float4*)&s_w[kr][c4] = wv;
        }
        __syncthreads();
        for (int k = 0; k < 32; ++k) {
            float4 wv = *(const float4*)&s_w[k][f0];
            #pragma unroll
            for (int ii = 0; ii < 4; ++ii) {
                float4 hv = *(const float4*)&s_h[k][b0 + ii * 4];
                float hvv[4] = {hv.x, hv.y, hv.z, hv.w};
                #pragma unroll
                for (int l = 0; l < 4; ++l) {
                    acc[ii * 4 + l][0] += hvv[l] * wv.x;
                    acc[ii * 4 + l][1] += hvv[l] * wv.y;
                    acc[ii * 4 + l][2] += hvv[l] * wv.z;
                    acc[ii * 4 + l][3] += hvv[l] * wv.w;
                }
            }
        }
        __syncthreads();
    }

    float* pp = partial + (size_t)blockIdx.x * 16384;
    #pragma unroll
    for (int i = 0; i < 16; ++i) {
        float4 v = make_float4(acc[i][0], acc[i][1], acc[i][2], acc[i][3]);
        *(float4*)&pp[(b0 + i) * 64 + f0] = v;
    }
}

// Stage 2: reduce 256 partials, + bias, relu, write r into out[b*128 + f].
__global__ __launch_bounds__(256)
void lin_reduce_k(const float* __restrict__ partial,
                  const float* __restrict__ lb,
                  float* __restrict__ out)
{
    int idx = blockIdx.x * 256 + threadIdx.x;   // 16384
    int b = idx >> 6, f = idx & 63;
    float s = lb[f];
    for (int c = 0; c < 256; ++c) s += partial[(size_t)c * 16384 + idx];
    out[(size_t)b * 128 + f] = fmaxf(s, 0.f);
}

// w = [x | r | m] @ write_w + write_b  -> out[b*128 + 64 + f]
__global__ __launch_bounds__(256)
void write_k(const float* __restrict__ x,
             const float* __restrict__ state,
             const int* __restrict__ index,
             const float* __restrict__ ww,
             const float* __restrict__ wb,
             float* __restrict__ out)
{
    int idx = blockIdx.x * 256 + threadIdx.x;   // 16384
    int b = idx >> 6, f = idx & 63;
    int i0 = index[b * 2 + 0];
    int i1 = index[b * 2 + 1];
    float s = wb[f];
    for (int k = 0; k < 256; ++k) s += x[(size_t)b * 256 + k] * ww[k * 64 + f];
    for (int k = 0; k < 64; ++k)  s += out[(size_t)b * 128 + k] * ww[(256 + k) * 64 + f];
    const float* mp = state + (size_t)b * 262144 + (size_t)i0 * 64 + i1;
    for (int k = 0; k < 64; ++k)  s += mp[(size_t)k * 4096] * ww[(320 + k) * 64 + f];
    out[(size_t)b * 128 + 64 + f] = s;
}

__global__ __launch_bounds__(256)
void copy_state_k(const float4* __restrict__ src, float4* __restrict__ dst, int n4)
{
    int stride = gridDim.x * blockDim.x;
    for (int i = blockIdx.x * blockDim.x + threadIdx.x; i < n4; i += stride)
        dst[i] = src[i];
}

__global__ __launch_bounds__(256)
void scatter_k(const int* __restrict__ index,
               const float* __restrict__ out_ro,
               float* __restrict__ ns)
{
    int idx = blockIdx.x * 256 + threadIdx.x;   // 16384
    int b = idx >> 6, f = idx & 63;
    int i0 = index[b * 2 + 0];
    int i1 = index[b * 2 + 1];
    ns[(((size_t)b * 64 + f) * 64 + i0) * 64 + i1] = out_ro[(size_t)b * 128 + 64 + f];
}

extern "C" void kernel_launch(void* const* d_in, const int* in_sizes, int n_in,
                              void* d_out, int out_size, void* d_ws, size_t ws_size,
                              hipStream_t stream)
{
    (void)in_sizes; (void)n_in; (void)out_size; (void)d_ws; (void)ws_size;
    const float* x     = (const float*)d_in[0];
    const float* state = (const float*)d_in[1];
    const int*   idx   = (const int*)d_in[2];
    const float* c1w   = (const float*)d_in[3];
    const float* c1b   = (const float*)d_in[4];
    const float* c2w   = (const float*)d_in[5];
    const float* c2b   = (const float*)d_in[6];
    const float* c3w   = (const float*)d_in[7];
    const float* c3b   = (const float*)d_in[8];
    const float* lw    = (const float*)d_in[9];
    const float* lb    = (const float*)d_in[10];
    const float* ww    = (const float*)d_in[11];
    const float* wb    = (const float*)d_in[12];

    float* out = (float*)d_out;
    float* ns  = out + 32768;                       // new_state region = scratch until copy

    // Repacked weights: 36,864 bf16 = 72 KB in the out region.
    __hip_bfloat16* rw  = (__hip_bfloat16*)out;
    __hip_bfloat16* rw1 = rw;                       // 18432 elems (CIN=64, 2 chunks)
    __hip_bfloat16* rw2 = rw + 18432;               // 9216
    __hip_bfloat16* rw3 = rw + 27648;               // 9216

    // Scratch inside new_state region (256 MB):
    __hip_bfloat16* h1    = (__hip_bfloat16*)ns;              // [0, 64MB)
    __hip_bfloat16* h2    = h1 + 33554432;                    // [64, 128MB)
    __hip_bfloat16* h3    = h1;                               // conv3 output reuses h1
    __hip_bfloat16* snhwc = (__hip_bfloat16*)(ns + 33554432); // [128, 256MB): NHWC bf16 state
    float* partial        = (float*)h2;                       // 16MB, reuses h2 after conv3

    repack_w_k    <<<144, 256, 0, stream>>>(c1w, c2w, c3w, rw);
    nchw_to_nhwc_k<<<16384, 256, 0, stream>>>(state, snhwc);
    conv_mfma_k<64><<<dim3(256, 8), 256, 0, stream>>>(snhwc, rw1, c1b, h1);
    conv_mfma_k<32><<<dim3(256, 8), 256, 0, stream>>>(h1, rw2, c2b, h2);
    conv_mfma_k<32><<<dim3(256, 8), 256, 0, stream>>>(h2, rw3, c3b, h3);
    lin_partial_k<<<256, 256, 0, stream>>>(h3, lw, partial);
    lin_reduce_k <<<64, 256, 0, stream>>>(partial, lb, out);
    write_k      <<<64, 256, 0, stream>>>(x, state, idx, ww, wb, out);
    copy_state_k <<<8192, 256, 0, stream>>>((const float4*)state, (float4*)ns, 16777216);
    scatter_k    <<<64, 256, 0, stream>>>(idx, out, ns);
}

// Round 4
// 778.411 us; speedup vs baseline: 3.7762x; 1.0871x over previous
//
#include <hip/hip_runtime.h>
#include <hip/hip_bf16.h>

// Problem constants: B=256, F=64, H=W=64, D=256, HC=32
// d_in: 0:x(256,256) 1:state(256,64,64,64) 2:index(256,2) 3:c1w 4:c1b 5:c2w 6:c2b
//       7:c3w 8:c3b 9:lin_w(131072,64) 10:lin_b 11:write_w(384,64) 12:write_b
// d_out: out(256,128) fp32 ++ new_state(256,64,64,64) fp32
//
// Preferred path (ws_size >= 256 MB): scratch in d_ws
//   ws[  0,128MB) snhwc (NHWC bf16 state)
//   ws[128,192MB) h1 (= h3 output region)
//   ws[192,256MB) h2 (later reused as partial)
//   head kernel reads state ONCE -> writes new_state fp32 copy + snhwc.
// Fallback (small ws): round-3 layout, scratch inside new_state region.
// Repacked conv weights (72 KB) live in the out region (rewritten by tail).

typedef __attribute__((ext_vector_type(8))) short bf16x8;
typedef __attribute__((ext_vector_type(4))) float f32x4;

__device__ inline unsigned short f2bfu(float f) {
    __hip_bfloat16 h = __float2bfloat16(f);
    return *reinterpret_cast<unsigned short*>(&h);
}

// ---------------------------------------------------------------------------
// Weight repack: (32, CIN, 3, 3) fp32 -> [ch][ks][co][ci_l] bf16, MFMA A-frag
// order: lane (co = l&15 (+16*cg), ci slice = (l>>4)*8) reads 16B contiguous.
// ---------------------------------------------------------------------------
__global__ __launch_bounds__(256)
void repack_w_k(const float* __restrict__ w1, const float* __restrict__ w2,
                const float* __restrict__ w3, __hip_bfloat16* __restrict__ rw)
{
    int idx = blockIdx.x * 256 + threadIdx.x;          // 36864 total
    const float* src; int CIN, li;
    if (idx < 18432)      { src = w1; CIN = 64; li = idx; }
    else if (idx < 27648) { src = w2; CIN = 32; li = idx - 18432; }
    else                  { src = w3; CIN = 32; li = idx - 27648; }
    int ci = li & 31;
    int co = (li >> 5) & 31;
    int t2 = li >> 10;            // = ch*9 + ks
    int ks = t2 % 9;
    int ch = t2 / 9;
    rw[idx] = __float2bfloat16(src[((size_t)(co * CIN + ch * 32 + ci)) * 9 + ks]);
}

// ---------------------------------------------------------------------------
// HEAD (ws path): read state once -> (a) fp32 copy into new_state,
// (b) NHWC bf16 transpose into snhwc. One block per (b, y).
// ---------------------------------------------------------------------------
__global__ __launch_bounds__(256)
void copy_transpose_k(const float* __restrict__ in,        // (256,64,64,64) NCHW
                      float* __restrict__ nsd,             // fp32 copy (NCHW)
                      __hip_bfloat16* __restrict__ outp)   // (256,y,x,c) bf16
{
    __shared__ unsigned short s[64][72];   // bf16 [c][x]
    const int blk = blockIdx.x;            // 16384 = 256 b * 64 y
    const int b = blk >> 6, y = blk & 63;
    const int t = threadIdx.x;

    const float* src = in  + (size_t)b * 262144 + (size_t)y * 64;   // + c*4096 + x
    float*       dst = nsd + (size_t)b * 262144 + (size_t)y * 64;
    #pragma unroll
    for (int q = 0; q < 4; ++q) {
        int c = q * 16 + (t >> 4);
        int x = (t & 15) * 4;
        float4 v = *(const float4*)(src + (size_t)c * 4096 + x);
        *(float4*)(dst + (size_t)c * 4096 + x) = v;
        *(ushort4*)&s[c][x] = make_ushort4(f2bfu(v.x), f2bfu(v.y), f2bfu(v.z), f2bfu(v.w));
    }
    __syncthreads();

    __hip_bfloat16* dq = outp + ((size_t)b * 4096 + y * 64) * 64;   // + x*64 + c
    #pragma unroll
    for (int q = 0; q < 4; ++q) {
        int x = q * 16 + (t >> 4);
        int c = (t & 15) * 4;
        ushort4 o = make_ushort4(s[c + 0][x], s[c + 1][x], s[c + 2][x], s[c + 3][x]);
        *(ushort4*)(dq + (size_t)x * 64 + c) = o;
    }
}

// Fallback prepass: NCHW fp32 -> NHWC bf16 only.
__global__ __launch_bounds__(256)
void nchw_to_nhwc_k(const float* __restrict__ in,
                    __hip_bfloat16* __restrict__ outp)
{
    __shared__ unsigned short s[64][72];
    const int blk = blockIdx.x;
    const int b = blk >> 6, y = blk & 63;
    const int t = threadIdx.x;

    const float* src = in + (size_t)b * 262144 + (size_t)y * 64;
    #pragma unroll
    for (int q = 0; q < 4; ++q) {
        int c = q * 16 + (t >> 4);
        int x = (t & 15) * 4;
        float4 v = *(const float4*)(src + (size_t)c * 4096 + x);
        *(ushort4*)&s[c][x] = make_ushort4(f2bfu(v.x), f2bfu(v.y), f2bfu(v.z), f2bfu(v.w));
    }
    __syncthreads();

    __hip_bfloat16* dst = outp + ((size_t)b * 4096 + y * 64) * 64;
    #pragma unroll
    for (int q = 0; q < 4; ++q) {
        int x = q * 16 + (t >> 4);
        int c = (t & 15) * 4;
        ushort4 o = make_ushort4(s[c + 0][x], s[c + 1][x], s[c + 2][x], s[c + 3][x]);
        *(ushort4*)(dst + (size_t)x * 64 + c) = o;
    }
}

// ---------------------------------------------------------------------------
// Implicit-GEMM 3x3 SAME conv + bias + relu via MFMA 16x16x32 bf16.
// Block: 256 thr (4 waves), one image, 16(y)x32(x) tile, all 32 co.
// Weights in registers; input tile in LDS [18][34][40] bf16 (px stride 80 B).
// 3 blocks/CU (LDS 49KB*3 = 147KB).
// ---------------------------------------------------------------------------
template<int CIN>
__global__ __launch_bounds__(256, 3)
void conv_mfma_k(const __hip_bfloat16* __restrict__ in,   // (256,64,64,CIN) NHWC
                 const __hip_bfloat16* __restrict__ rw,   // [CIN/32][9][32][32]
                 const float* __restrict__ bias,          // (32)
                 __hip_bfloat16* __restrict__ out)        // (256,64,64,32) NHWC
{
    constexpr int NCH = CIN / 32;
    __shared__ __hip_bfloat16 s_in[18 * 34 * 40];   // 48,960 B

    const int b    = blockIdx.x;
    const int ty0  = (blockIdx.y >> 1) * 16;
    const int tx0  = (blockIdx.y & 1) * 32;
    const int t    = threadIdx.x;
    const int lane = t & 63;
    const int wv   = t >> 6;
    const int ln   = lane & 15;
    const int lg   = lane >> 4;

    const f32x4 zero4 = {0.f, 0.f, 0.f, 0.f};
    f32x4 acc[8][2];
    #pragma unroll
    for (int p = 0; p < 8; ++p) { acc[p][0] = zero4; acc[p][1] = zero4; }

    int bbase[8];
    #pragma unroll
    for (int p = 0; p < 8; ++p) {
        int gg = wv * 8 + p;
        bbase[p] = (((gg >> 1) * 34) + (gg & 1) * 16 + ln) * 80 + lg * 16;
    }

    for (int ch = 0; ch < NCH; ++ch) {
        bf16x8 wf[9][2];
        #pragma unroll
        for (int ks = 0; ks < 9; ++ks)
            #pragma unroll
            for (int cg = 0; cg < 2; ++cg)
                wf[ks][cg] = *(const bf16x8*)(rw + ((size_t)((ch * 9 + ks) * 32 + cg * 16 + ln)) * 32 + lg * 8);

        // stage halo tile: 612 px x 4 chunks of 16B = 2448 ids; batch loads.
        uint4 vreg[10];
        #pragma unroll
        for (int q = 0; q < 10; ++q) {
            int id = q * 256 + t;
            uint4 v = make_uint4(0u, 0u, 0u, 0u);
            if (id < 2448) {
                int c8 = id & 3, px = id >> 2;
                int ly = px / 34, lx = px - ly * 34;
                int gy = ty0 - 1 + ly, gx = tx0 - 1 + lx;
                if ((unsigned)gy < 64u && (unsigned)gx < 64u)
                    v = *(const uint4*)(in + ((size_t)b * 4096 + gy * 64 + gx) * CIN + ch * 32 + c8 * 8);
            }
            vreg[q] = v;
        }
        #pragma unroll
        for (int q = 0; q < 10; ++q) {
            int id = q * 256 + t;
            if (id < 2448) {
                int c8 = id & 3, px = id >> 2;
                *(uint4*)(reinterpret_cast<char*>(s_in) + px * 80 + c8 * 16) = vreg[q];
            }
        }
        __syncthreads();

        #pragma unroll
        for (int ky = 0; ky < 3; ++ky)
        #pragma unroll
        for (int kx = 0; kx < 3; ++kx) {
            const int ks   = ky * 3 + kx;
            const int koff = (ky * 34 + kx) * 80;
            #pragma unroll
            for (int p = 0; p < 8; ++p) {
                bf16x8 bfr = *(const bf16x8*)(reinterpret_cast<const char*>(s_in) + bbase[p] + koff);
                acc[p][0] = __builtin_amdgcn_mfma_f32_16x16x32_bf16(wf[ks][0], bfr, acc[p][0], 0, 0, 0);
                acc[p][1] = __builtin_amdgcn_mfma_f32_16x16x32_bf16(wf[ks][1], bfr, acc[p][1], 0, 0, 0);
            }
        }
        __syncthreads();
    }

    #pragma unroll
    for (int p = 0; p < 8; ++p) {
        int gg = wv * 8 + p;
        int y  = ty0 + (gg >> 1);
        int x  = tx0 + (gg & 1) * 16 + ln;
        size_t pxb = ((size_t)b * 4096 + y * 64 + x) * 32;
        #pragma unroll
        for (int cg = 0; cg < 2; ++cg) {
            int co0 = cg * 16 + lg * 4;   // D row = (lane>>4)*4 + reg
            float4 bv = *(const float4*)(bias + co0);
            ushort4 o;
            o.x = f2bfu(fmaxf(acc[p][cg][0] + bv.x, 0.f));
            o.y = f2bfu(fmaxf(acc[p][cg][1] + bv.y, 0.f));
            o.z = f2bfu(fmaxf(acc[p][cg][2] + bv.z, 0.f));
            o.w = f2bfu(fmaxf(acc[p][cg][3] + bv.w, 0.f));
            *(ushort4*)(out + pxb + co0) = o;
        }
    }
}

// ---------------------------------------------------------------------------
// Linear stage 1: split-K GEMM. M=256(b) N=64(f) K=131072. h3 is NHWC bf16,
// so k enumerates (yx, co); lin_w row = co*4096 + yx (NCHW flattening).
// ---------------------------------------------------------------------------
__global__ __launch_bounds__(256)
void lin_partial_k(const __hip_bfloat16* __restrict__ h3,  // (256, 131072) NHWC order
                   const float* __restrict__ lw,           // (131072, 64) NCHW order
                   float* __restrict__ partial)            // (256, 256*64)
{
    __shared__ float s_h[32][260];
    __shared__ float s_w[32][64];
    const int t  = threadIdx.x;
    const int k0 = blockIdx.x * 512;
    const int f0 = (t & 15) * 4;
    const int b0 = (t >> 4) * 16;

    float acc[16][4];
    #pragma unroll
    for (int i = 0; i < 16; ++i)
        #pragma unroll
        for (int j = 0; j < 4; ++j) acc[i][j] = 0.f;

    for (int kk = 0; kk < 512; kk += 32) {
        #pragma unroll
        for (int i = 0; i < 8; ++i) {
            int id = i * 256 + t;
            int bb = id >> 3;
            int pc = id & 7;
            ushort4 hv = *(const ushort4*)(h3 + (size_t)bb * 131072 + k0 + kk + pc * 4);
            s_h[pc * 4 + 0][bb] = __uint_as_float((unsigned)hv.x << 16);
            s_h[pc * 4 + 1][bb] = __uint_as_float((unsigned)hv.y << 16);
            s_h[pc * 4 + 2][bb] = __uint_as_float((unsigned)hv.z << 16);
            s_h[pc * 4 + 3][bb] = __uint_as_float((unsigned)hv.w << 16);
        }
        #pragma unroll
        for (int i = 0; i < 2; ++i) {
            int id = i * 256 + t;
            int kr = id >> 4;
            int c4 = (id & 15) * 4;
            int k  = k0 + kk + kr;
            size_t ref = (size_t)(k & 31) * 4096 + (size_t)(k >> 5);   // co*4096 + yx
            float4 wv = *(const float4*)&lw[ref * 64 + c4];
            *(float4*)&s_w[kr][c4] = wv;
        }
        __syncthreads();
        for (int k = 0; k < 32; ++k) {
            float4 wv = *(const float4*)&s_w[k][f0];
            #pragma unroll
            for (int ii = 0; ii < 4; ++ii) {
                float4 hv = *(const float4*)&s_h[k][b0 + ii * 4];
                float hvv[4] = {hv.x, hv.y, hv.z, hv.w};
                #pragma unroll
                for (int l = 0; l < 4; ++l) {
                    acc[ii * 4 + l][0] += hvv[l] * wv.x;
                    acc[ii * 4 + l][1] += hvv[l] * wv.y;
                    acc[ii * 4 + l][2] += hvv[l] * wv.z;
                    acc[ii * 4 + l][3] += hvv[l] * wv.w;
                }
            }
        }
        __syncthreads();
    }

    float* pp = partial + (size_t)blockIdx.x * 16384;
    #pragma unroll
    for (int i = 0; i < 16; ++i) {
        float4 v = make_float4(acc[i][0], acc[i][1], acc[i][2], acc[i][3]);
        *(float4*)&pp[(b0 + i) * 64 + f0] = v;
    }
}

// ---------------------------------------------------------------------------
// TAIL (fused lin_reduce + write + scatter). 64 blocks x 256 thr; block = 4 b.
// Phase 1: r = relu(sum partials + lb) -> out + LDS.  Phase 2: w -> out + ns.
// ---------------------------------------------------------------------------
__global__ __launch_bounds__(256)
void tail_k(const float* __restrict__ partial,
            const float* __restrict__ lb,
            const float* __restrict__ x,
            const float* __restrict__ state,
            const int* __restrict__ index,
            const float* __restrict__ ww,
            const float* __restrict__ wb,
            float* __restrict__ out,
            float* __restrict__ ns)
{
    __shared__ float r_s[4][64];
    const int t  = threadIdx.x;
    const int bl = t >> 6;
    const int f  = t & 63;
    const int b  = blockIdx.x * 4 + bl;

    // phase 1: reduce partials
    float s = lb[f];
    const float* pp = partial + (size_t)b * 64 + f;
    for (int c = 0; c < 256; ++c) s += pp[(size_t)c * 16384];
    float r = fmaxf(s, 0.f);
    out[(size_t)b * 128 + f] = r;
    r_s[bl][f] = r;
    __syncthreads();

    // phase 2: w = [x | r | m] @ ww + wb
    int i0 = index[b * 2 + 0];
    int i1 = index[b * 2 + 1];
    float w = wb[f];
    const float* xb = x + (size_t)b * 256;
    for (int k = 0; k < 256; ++k) w += xb[k] * ww[k * 64 + f];
    for (int k = 0; k < 64; ++k)  w += r_s[bl][k] * ww[(256 + k) * 64 + f];
    const float* mp = state + (size_t)b * 262144 + (size_t)i0 * 64 + i1;
    for (int k = 0; k < 64; ++k)  w += mp[(size_t)k * 4096] * ww[(320 + k) * 64 + f];
    out[(size_t)b * 128 + 64 + f] = w;
    ns[(((size_t)b * 64 + f) * 64 + i0) * 64 + i1] = w;
}

// Fallback-path kernels (round-3 sequence):
__global__ __launch_bounds__(256)
void lin_reduce_k(const float* __restrict__ partial,
                  const float* __restrict__ lb,
                  float* __restrict__ out)
{
    int idx = blockIdx.x * 256 + threadIdx.x;
    int b = idx >> 6, f = idx & 63;
    float s = lb[f];
    for (int c = 0; c < 256; ++c) s += partial[(size_t)c * 16384 + idx];
    out[(size_t)b * 128 + f] = fmaxf(s, 0.f);
}

__global__ __launch_bounds__(256)
void write_k(const float* __restrict__ x,
             const float* __restrict__ state,
             const int* __restrict__ index,
             const float* __restrict__ ww,
             const float* __restrict__ wb,
             float* __restrict__ out)
{
    int idx = blockIdx.x * 256 + threadIdx.x;
    int b = idx >> 6, f = idx & 63;
    int i0 = index[b * 2 + 0];
    int i1 = index[b * 2 + 1];
    float s = wb[f];
    for (int k = 0; k < 256; ++k) s += x[(size_t)b * 256 + k] * ww[k * 64 + f];
    for (int k = 0; k < 64; ++k)  s += out[(size_t)b * 128 + k] * ww[(256 + k) * 64 + f];
    const float* mp = state + (size_t)b * 262144 + (size_t)i0 * 64 + i1;
    for (int k = 0; k < 64; ++k)  s += mp[(size_t)k * 4096] * ww[(320 + k) * 64 + f];
    out[(size_t)b * 128 + 64 + f] = s;
}

__global__ __launch_bounds__(256)
void copy_state_k(const float4* __restrict__ src, float4* __restrict__ dst, int n4)
{
    int stride = gridDim.x * blockDim.x;
    for (int i = blockIdx.x * blockDim.x + threadIdx.x; i < n4; i += stride)
        dst[i] = src[i];
}

__global__ __launch_bounds__(256)
void scatter_k(const int* __restrict__ index,
               const float* __restrict__ out_ro,
               float* __restrict__ ns)
{
    int idx = blockIdx.x * 256 + threadIdx.x;
    int b = idx >> 6, f = idx & 63;
    int i0 = index[b * 2 + 0];
    int i1 = index[b * 2 + 1];
    ns[(((size_t)b * 64 + f) * 64 + i0) * 64 + i1] = out_ro[(size_t)b * 128 + 64 + f];
}

extern "C" void kernel_launch(void* const* d_in, const int* in_sizes, int n_in,
                              void* d_out, int out_size, void* d_ws, size_t ws_size,
                              hipStream_t stream)
{
    (void)in_sizes; (void)n_in; (void)out_size;
    const float* x     = (const float*)d_in[0];
    const float* state = (const float*)d_in[1];
    const int*   idx   = (const int*)d_in[2];
    const float* c1w   = (const float*)d_in[3];
    const float* c1b   = (const float*)d_in[4];
    const float* c2w   = (const float*)d_in[5];
    const float* c2b   = (const float*)d_in[6];
    const float* c3w   = (const float*)d_in[7];
    const float* c3b   = (const float*)d_in[8];
    const float* lw    = (const float*)d_in[9];
    const float* lb    = (const float*)d_in[10];
    const float* ww    = (const float*)d_in[11];
    const float* wb    = (const float*)d_in[12];

    float* out = (float*)d_out;
    float* ns  = out + 32768;                       // new_state region

    // Repacked conv weights: 72 KB in the out region (out rewritten by tail).
    __hip_bfloat16* rw  = (__hip_bfloat16*)out;
    __hip_bfloat16* rw1 = rw;
    __hip_bfloat16* rw2 = rw + 18432;
    __hip_bfloat16* rw3 = rw + 27648;

    const size_t WS_NEED = 268435456;               // 256 MB
    if (d_ws != nullptr && ws_size >= WS_NEED) {
        // ---- ws path: scratch in workspace, state read once.
        __hip_bfloat16* snhwc = (__hip_bfloat16*)d_ws;            // [0,128MB)
        __hip_bfloat16* h1    = snhwc + 67108864;                 // [128,192MB)
        __hip_bfloat16* h2    = h1 + 33554432;                    // [192,256MB)
        __hip_bfloat16* h3    = h1;                               // conv3 out reuses h1
        float* partial        = (float*)h2;                       // 16MB, after conv3

        repack_w_k      <<<144, 256, 0, stream>>>(c1w, c2w, c3w, rw);
        copy_transpose_k<<<16384, 256, 0, stream>>>(state, ns, snhwc);
        conv_mfma_k<64> <<<dim3(256, 8), 256, 0, stream>>>(snhwc, rw1, c1b, h1);
        conv_mfma_k<32> <<<dim3(256, 8), 256, 0, stream>>>(h1, rw2, c2b, h2);
        conv_mfma_k<32> <<<dim3(256, 8), 256, 0, stream>>>(h2, rw3, c3b, h3);
        lin_partial_k   <<<256, 256, 0, stream>>>(h3, lw, partial);
        tail_k          <<<64, 256, 0, stream>>>(partial, lb, x, state, idx, ww, wb, out, ns);
    } else {
        // ---- fallback: round-3 sequence, scratch inside new_state region.
        __hip_bfloat16* h1    = (__hip_bfloat16*)ns;              // [0, 64MB)
        __hip_bfloat16* h2    = h1 + 33554432;                    // [64, 128MB)
        __hip_bfloat16* h3    = h1;
        __hip_bfloat16* snhwc = (__hip_bfloat16*)(ns + 33554432); // [128, 256MB)
        float* partial        = (float*)h2;

        repack_w_k    <<<144, 256, 0, stream>>>(c1w, c2w, c3w, rw);
        nchw_to_nhwc_k<<<16384, 256, 0, stream>>>(state, snhwc);
        conv_mfma_k<64><<<dim3(256, 8), 256, 0, stream>>>(snhwc, rw1, c1b, h1);
        conv_mfma_k<32><<<dim3(256, 8), 256, 0, stream>>>(h1, rw2, c2b, h2);
        conv_mfma_k<32><<<dim3(256, 8), 256, 0, stream>>>(h2, rw3, c3b, h3);
        lin_partial_k<<<256, 256, 0, stream>>>(h3, lw, partial);
        lin_reduce_k <<<64, 256, 0, stream>>>(partial, lb, out);
        write_k      <<<64, 256, 0, stream>>>(x, state, idx, ww, wb, out);
        copy_state_k <<<8192, 256, 0, stream>>>((const float4*)state, (float4*)ns, 16777216);
        scatter_k    <<<64, 256, 0, stream>>>(idx, out, ns);
    }
}